// Round 1
// baseline (12712.651 us; speedup 1.0000x reference)
//
#include <hip/hip_runtime.h>

#define NHID   128
#define NG     384          // 3*NHID
#define NSTEPS 512          // N lattice sites
#define NSAMP  4096
#define SPB    16           // samples per block
#define NBLK   256          // blocks (1 per CU)
#define BS     512          // threads per block (8 waves)
#define SAMP_ELEMS (NSAMP * NSTEPS)

// one k-row partial: 3 gate quads, 12 FMAs
#define KSTEP(HK, WPTR) do {                                              \
    const float4 w0 = *(const float4*)(WPTR);                             \
    const float4 w1 = *(const float4*)((WPTR) + NHID);                    \
    const float4 w2 = *(const float4*)((WPTR) + 2*NHID);                  \
    az[0] = fmaf((HK), w0.x, az[0]); az[1] = fmaf((HK), w0.y, az[1]);     \
    az[2] = fmaf((HK), w0.z, az[2]); az[3] = fmaf((HK), w0.w, az[3]);     \
    ar[0] = fmaf((HK), w1.x, ar[0]); ar[1] = fmaf((HK), w1.y, ar[1]);     \
    ar[2] = fmaf((HK), w1.z, ar[2]); ar[3] = fmaf((HK), w1.w, ar[3]);     \
    ah[0] = fmaf((HK), w2.x, ah[0]); ah[1] = fmaf((HK), w2.y, ah[1]);     \
    ah[2] = fmaf((HK), w2.z, ah[2]); ah[3] = fmaf((HK), w2.w, ah[3]);     \
} while (0)

__global__ __launch_bounds__(BS, 1)
void vmc_gru_kernel(const float* __restrict__ gk,   // (2, 384)
                    const float* __restrict__ rk,   // (128, 384)
                    const float* __restrict__ gb,   // (2, 384)
                    const float* __restrict__ dw,   // (128, 2)
                    const float* __restrict__ db,   // (2,)
                    const float* __restrict__ u,    // (4096, 512)
                    float* __restrict__ out)        // samples (4096*512) then logp (4096)
{
    // XT[i][c] = b_in[c] + Wk[i][c] for i=0,1 ; XT[2][c] = b_in[c] (t==0, x=0)
    __shared__ float XT[3][NG];
    __shared__ float hsm[SPB][NHID];

    const int tid = threadIdx.x;
    for (int c = tid; c < NG; c += BS) {
        const float bi = gb[c];
        XT[0][c] = bi + gk[c];
        XT[1][c] = bi + gk[NG + c];
        XT[2][c] = bi;
    }
    for (int i = tid; i < SPB * NHID; i += BS) (&hsm[0][0])[i] = 0.0f;
    __syncthreads();

    const int s    = tid >> 5;          // sample within block (0..15)
    const int ls   = tid & 31;          // lane within sample group
    const int samp = blockIdx.x * SPB + s;
    const int j0   = ls * 4;            // 4 channels per lane per gate

    // constants hoisted to registers
    float dw0[4], dw1[4];
    #pragma unroll
    for (int m = 0; m < 4; ++m) {
        dw0[m] = dw[(j0 + m) * 2 + 0];
        dw1[m] = dw[(j0 + m) * 2 + 1];
    }
    const float db0 = db[0], db1 = db[1];
    // b_rec quads (fold into accumulator init)
    const float4 bz4 = *(const float4*)(gb + NG + j0);
    const float4 br4 = *(const float4*)(gb + NG + NHID + j0);
    const float4 bh4 = *(const float4*)(gb + NG + 2*NHID + j0);

    float* hrow = hsm[s];
    const float* urow = u + (size_t)samp * NSTEPS;
    float* srow = out + (size_t)samp * NSTEPS;

    int prev = 2;           // t=0: x = 0 -> XT row 2
    float logp = 0.0f;

    for (int t = 0; t < NSTEPS; ++t) {
        // hg = h @ Wr + b_rec   (lane's 4 channels per gate)
        float az[4] = {bz4.x, bz4.y, bz4.z, bz4.w};
        float ar[4] = {br4.x, br4.y, br4.z, br4.w};
        float ah[4] = {bh4.x, bh4.y, bh4.z, bh4.w};

        const float* wbase = rk + j0;
        #pragma unroll 4
        for (int k4 = 0; k4 < NHID; k4 += 4) {
            const float4 hv = *(const float4*)(hrow + k4);
            const float* wp = wbase + (size_t)k4 * NG;
            KSTEP(hv.x, wp);
            KSTEP(hv.y, wp + NG);
            KSTEP(hv.z, wp + 2 * NG);
            KSTEP(hv.w, wp + 3 * NG);
        }

        // gates + state update
        const float* xt = XT[prev];
        const float4 xz4 = *(const float4*)(xt + j0);
        const float4 xr4 = *(const float4*)(xt + NHID + j0);
        const float4 xh4 = *(const float4*)(xt + 2*NHID + j0);
        const float4 hold = *(const float4*)(hrow + j0);
        const float xzv[4] = {xz4.x, xz4.y, xz4.z, xz4.w};
        const float xrv[4] = {xr4.x, xr4.y, xr4.z, xr4.w};
        const float xhv[4] = {xh4.x, xh4.y, xh4.z, xh4.w};
        const float hov[4] = {hold.x, hold.y, hold.z, hold.w};
        float hn[4];
        float pl0 = 0.0f, pl1 = 0.0f;
        #pragma unroll
        for (int m = 0; m < 4; ++m) {
            const float z  = 1.0f / (1.0f + expf(-(xzv[m] + az[m])));
            const float r  = 1.0f / (1.0f + expf(-(xrv[m] + ar[m])));
            const float hc = tanhf(xhv[m] + r * ah[m]);
            const float hnew = z * hov[m] + (1.0f - z) * hc;
            hn[m] = hnew;
            pl0 = fmaf(hnew, dw0[m], pl0);
            pl1 = fmaf(hnew, dw1[m], pl1);
        }
        *(float4*)(hrow + j0) = make_float4(hn[0], hn[1], hn[2], hn[3]);

        // reduce logits across the 32-lane sample group (butterfly; all lanes get sums)
        #pragma unroll
        for (int off = 1; off < 32; off <<= 1) {
            pl0 += __shfl_xor(pl0, off);
            pl1 += __shfl_xor(pl1, off);
        }

        // softmax over 2 classes + sample + logp
        const float l0 = pl0 + db0;
        const float l1 = pl1 + db1;
        const float mx = fmaxf(l0, l1);
        const float e0 = expf(l0 - mx);
        const float e1 = expf(l1 - mx);
        const float inv = 1.0f / (e0 + e1);
        const float p1 = e1 * inv;
        const float ut = urow[t];
        const int st = (ut < p1) ? 1 : 0;
        const float psel = st ? p1 : (e0 * inv);
        logp += logf(psel + 1e-10f);
        prev = st;
        if (ls == 0) srow[t] = (float)st;

        // keep the 8 waves in lockstep so Wr rows stay hot in L1
        __syncthreads();
    }

    if (ls == 0) out[SAMP_ELEMS + samp] = logp;
}

extern "C" void kernel_launch(void* const* d_in, const int* in_sizes, int n_in,
                              void* d_out, int out_size, void* d_ws, size_t ws_size,
                              hipStream_t stream) {
    const float* gk = (const float*)d_in[0];
    const float* rk = (const float*)d_in[1];
    const float* gb = (const float*)d_in[2];
    const float* dw = (const float*)d_in[3];
    const float* db = (const float*)d_in[4];
    const float* u  = (const float*)d_in[5];
    float* out = (float*)d_out;
    vmc_gru_kernel<<<NBLK, BS, 0, stream>>>(gk, rk, gb, dw, db, u, out);
}

// Round 2
// 4335.354 us; speedup vs baseline: 2.9323x; 2.9323x over previous
//
#include <hip/hip_runtime.h>

#define NHID   128
#define NSTEPS 512
#define NSAMP  4096
#define SPB    16
#define NBLK   256
#define BS     512
#define NWAVE  (BS/64)
#define SAMP_ELEMS (NSAMP * NSTEPS)

__global__ __launch_bounds__(BS, 1)
void vmc_gru_kernel(const float* __restrict__ gk,   // (2, 384)
                    const float* __restrict__ rk,   // (128, 384)
                    const float* __restrict__ gb,   // (2, 384)
                    const float* __restrict__ dw,   // (128, 2)
                    const float* __restrict__ db,   // (2,)
                    const float* __restrict__ u,    // (4096, 512)
                    float* __restrict__ out)        // samples (4096*512) then logp (4096)
{
    __shared__ float hsm[NHID * SPB];          // h[k][s]  (8 KB)
    __shared__ float part[NWAVE * SPB * 2];    // per-wave logit partials
    __shared__ int   prevs[SPB];

    const int tid = threadIdx.x;
    const int cg  = tid >> 2;        // channel 0..127 (one per gate: cg, cg+128, cg+256)
    const int sq  = tid & 3;         // sample-quad 0..3
    const int s0  = sq * 4;          // first sample of quad
    const int wv  = tid >> 6;        // wave id 0..7

    for (int i = tid; i < NHID * SPB; i += BS) hsm[i] = 0.0f;
    __syncthreads();

    // per-thread constants (channel cg of each gate)
    const float brz = gb[384 + cg];
    const float brr = gb[384 + 128 + cg];
    const float brh = gb[384 + 256 + cg];
    const float xzI = gb[cg],       xz0c = xzI + gk[cg],       xz1c = xzI + gk[384 + cg];
    const float xrI = gb[128 + cg], xr0c = xrI + gk[128 + cg], xr1c = xrI + gk[384 + 128 + cg];
    const float xhI = gb[256 + cg], xh0c = xhI + gk[256 + cg], xh1c = xhI + gk[384 + 256 + cg];
    const float dwc0 = dw[cg * 2], dwc1 = dw[cg * 2 + 1];
    const float db0 = db[0], db1 = db[1];

    const int fsamp = blockIdx.x * SPB + tid;   // valid only for tid < SPB
    float logp = 0.0f;

    for (int t = 0; t < NSTEPS; ++t) {
        // ---- GEMM: hg[cg|cg+128|cg+256][s0..s0+3] = b_rec + sum_k h[k][s]*W[k][c]
        // per-(c,s) chain: bias-init, k ascending, fmaf — bit-identical to prior kernel
        float az[4] = {brz, brz, brz, brz};
        float ar[4] = {brr, brr, brr, brr};
        float ah[4] = {brh, brh, brh, brh};
        const float* wp = rk + cg;
        const float* hp = hsm + s0;
        #pragma unroll 4
        for (int k = 0; k < NHID; ++k) {
            const float wz = wp[0];
            const float wr = wp[NHID];
            const float wh = wp[2 * NHID];
            const float4 hv = *(const float4*)hp;
            az[0] = fmaf(wz, hv.x, az[0]); az[1] = fmaf(wz, hv.y, az[1]);
            az[2] = fmaf(wz, hv.z, az[2]); az[3] = fmaf(wz, hv.w, az[3]);
            ar[0] = fmaf(wr, hv.x, ar[0]); ar[1] = fmaf(wr, hv.y, ar[1]);
            ar[2] = fmaf(wr, hv.z, ar[2]); ar[3] = fmaf(wr, hv.w, ar[3]);
            ah[0] = fmaf(wh, hv.x, ah[0]); ah[1] = fmaf(wh, hv.y, ah[1]);
            ah[2] = fmaf(wh, hv.z, ah[2]); ah[3] = fmaf(wh, hv.w, ah[3]);
            wp += 3 * NHID;
            hp += SPB;
        }
        __syncthreads();   // B1: all GEMM h-reads complete before h is overwritten

        // ---- gates + state update (fully in-register; thread owns (cg, 4 samples))
        const float4 ho = *(const float4*)(hsm + cg * SPB + s0);
        const int4  pv = *(const int4*)(prevs + s0);      // unused at t==0
        const float hov[4] = {ho.x, ho.y, ho.z, ho.w};
        const int   pvv[4] = {pv.x, pv.y, pv.z, pv.w};
        float hn[4], p0s[4], p1s[4];
        #pragma unroll
        for (int j = 0; j < 4; ++j) {
            float xz = pvv[j] ? xz1c : xz0c;
            float xr = pvv[j] ? xr1c : xr0c;
            float xh = pvv[j] ? xh1c : xh0c;
            if (t == 0) { xz = xzI; xr = xrI; xh = xhI; }
            const float z  = 1.0f / (1.0f + expf(-(xz + az[j])));
            const float r  = 1.0f / (1.0f + expf(-(xr + ar[j])));
            const float hc = tanhf(xh + r * ah[j]);
            const float hnew = z * hov[j] + (1.0f - z) * hc;
            hn[j] = hnew;
            p0s[j] = hnew * dwc0;
            p1s[j] = hnew * dwc1;
        }
        *(float4*)(hsm + cg * SPB + s0) = make_float4(hn[0], hn[1], hn[2], hn[3]);

        // reduce logit partials over the 16 channels in this wave (lane bits [5:2] = cg)
        #pragma unroll
        for (int off = 4; off < 64; off <<= 1) {
            #pragma unroll
            for (int j = 0; j < 4; ++j) {
                p0s[j] += __shfl_xor(p0s[j], off);
                p1s[j] += __shfl_xor(p1s[j], off);
            }
        }
        if ((tid & 63) < 4) {
            float* pp = part + wv * (SPB * 2) + s0 * 2;
            #pragma unroll
            for (int j = 0; j < 4; ++j) {
                pp[j * 2 + 0] = p0s[j];
                pp[j * 2 + 1] = p1s[j];
            }
        }
        __syncthreads();   // B2: partials + h_new visible

        // ---- final: softmax over 2 classes, sample, logp (one thread per sample)
        if (tid < SPB) {
            float l0 = db0, l1 = db1;
            #pragma unroll
            for (int w = 0; w < NWAVE; ++w) {
                const float2 pw = *(const float2*)(part + w * (SPB * 2) + tid * 2);
                l0 += pw.x;
                l1 += pw.y;
            }
            const float mx = fmaxf(l0, l1);
            const float e0 = expf(l0 - mx);
            const float e1 = expf(l1 - mx);
            const float inv = 1.0f / (e0 + e1);
            const float p1 = e1 * inv;
            const float ut = u[(size_t)fsamp * NSTEPS + t];
            const int st = (ut < p1) ? 1 : 0;
            const float psel = st ? p1 : (e0 * inv);
            logp += logf(psel + 1e-10f);
            out[(size_t)fsamp * NSTEPS + t] = (float)st;
            prevs[tid] = st;
        }
    }

    if (tid < SPB) out[SAMP_ELEMS + fsamp] = logp;
}

extern "C" void kernel_launch(void* const* d_in, const int* in_sizes, int n_in,
                              void* d_out, int out_size, void* d_ws, size_t ws_size,
                              hipStream_t stream) {
    const float* gk = (const float*)d_in[0];
    const float* rk = (const float*)d_in[1];
    const float* gb = (const float*)d_in[2];
    const float* dw = (const float*)d_in[3];
    const float* db = (const float*)d_in[4];
    const float* u  = (const float*)d_in[5];
    float* out = (float*)d_out;
    vmc_gru_kernel<<<NBLK, BS, 0, stream>>>(gk, rk, gb, dw, db, u, out);
}